// Round 6
// baseline (238.119 us; speedup 1.0000x reference)
//
#include <hip/hip_runtime.h>
#include <math.h>

#define TSEQ   2048
#define BB     2
#define DMODEL 1024
#define NHEAD  16
#define DHEAD  64
#define MROWS  (TSEQ * BB)   // 4096
#define NQB    (TSEQ / 64)   // 32 query tiles per (b,h)

typedef __attribute__((ext_vector_type(8))) _Float16 half8;
typedef __attribute__((ext_vector_type(4))) float    floatx4;
typedef unsigned short u16;
typedef unsigned int   u32;

#define QSCL 11.5415603f   /* 8 * log2(e): Q pre-scale -> exp2-domain scores */
#define MSK  1442695.0f    /* 1e6 * log2(e) */

__device__ __forceinline__ u16 f2h(float f) {
    union { _Float16 h; u16 u; } cv;
    cv.h = (_Float16)f;
    return cv.u;
}

// packed fp32x2 -> fp16x2 (round-to-zero) as u32
__device__ __forceinline__ u32 pkrtz(float a, float b) {
    typedef __attribute__((ext_vector_type(2))) __fp16 fp16x2;
    union { fp16x2 h; u32 u; } cv;
    cv.h = __builtin_amdgcn_cvt_pkrtz(a, b);
    return cv.u;
}

__device__ __forceinline__ void async_cp16(const u16* g, u16* l) {
    __builtin_amdgcn_global_load_lds(
        (const __attribute__((address_space(1))) unsigned int*)g,
        (__attribute__((address_space(3))) unsigned int*)l, 16, 0, 0);
}

// ---------------------------------------------------------------------------
// one-launch fp32 -> fp16 cast of x, qkv_w, out_w
// float4 units: x 1048576, qkv_w 786432, out_w 262144 (total 2097152)
// ---------------------------------------------------------------------------
__global__ __launch_bounds__(256)
void cast3_f32_f16(const float* __restrict__ a, u16* __restrict__ oa,
                   const float* __restrict__ b, u16* __restrict__ ob,
                   const float* __restrict__ c, u16* __restrict__ oc)
{
    int i = blockIdx.x * 256 + threadIdx.x;
    const float* src; u16* dst; int off;
    if (i < 1048576)      { src = a; dst = oa; off = 0; }
    else if (i < 1835008) { src = b; dst = ob; off = 1048576; }
    else                  { src = c; dst = oc; off = 1835008; }
    int j = i - off;
    float4 v = ((const float4*)src)[j];
    ushort4 o;
    o.x = f2h(v.x); o.y = f2h(v.y); o.z = f2h(v.z); o.w = f2h(v.w);
    ((ushort4*)dst)[j] = o;
}

// ---------------------------------------------------------------------------
// fp16 MFMA GEMM, 128x128 tile, BK=64, global_load_lds + XOR-swizzled LDS.
// MODE 0 (out-proj): transposed orientation -> float4 stores of C=A*W^T+bias.
// MODE 1 (QKV):
//   c<2  (Q,K): transposed orientation; packed dwordx2 fp16 stores to
//               [b][h][t][d]; Q additionally scaled by QSCL.
//   c==2 (V):   normal orientation; packed dword stores to V^T [b][h][d][t].
// ---------------------------------------------------------------------------
template <int MODE>
__global__ __launch_bounds__(256)
void gemm_f16(const u16* __restrict__ A, const u16* __restrict__ W,
              const float* __restrict__ bias, float* __restrict__ Cout,
              u16* __restrict__ Qo, u16* __restrict__ Ko, u16* __restrict__ Vo,
              int M, int N, int K)
{
    __shared__ __align__(16) u16 As[128][64];
    __shared__ __align__(16) u16 Bs[128][64];

    const int tid  = threadIdx.x;
    const int lane = tid & 63;
    const int wv   = tid >> 6;
    const int wm   = wv >> 1, wn = wv & 1;
    const int ln   = lane & 15, lh = lane >> 4;
    const int m0   = blockIdx.y * 128;
    const int n0   = blockIdx.x * 128;

    const int c = (MODE == 1) ? (n0 >> 10) : 0;    // block-uniform
    const bool vmode = (MODE == 1) && (c == 2);    // normal orientation

    const int srow  = wv * 32 + (lane >> 3);
    const int sslot = lane & 7;

    const floatx4 zero4 = {0.0f, 0.0f, 0.0f, 0.0f};
    floatx4 acc[4][4];
#pragma unroll
    for (int i = 0; i < 4; ++i)
#pragma unroll
        for (int j = 0; j < 4; ++j) acc[i][j] = zero4;

    for (int k0 = 0; k0 < K; k0 += 64) {
        __syncthreads();
#pragma unroll
        for (int t = 0; t < 4; ++t) {
            const int row = srow + t * 8;
            const int g   = sslot ^ (row & 7);
            async_cp16(A + (size_t)(m0 + row) * K + k0 + g * 8, &As[row][sslot * 8]);
            async_cp16(W + (size_t)(n0 + row) * K + k0 + g * 8, &Bs[row][sslot * 8]);
        }
        __syncthreads();

#pragma unroll
        for (int ks = 0; ks < 2; ++ks) {
            half8 xf[4], wf[4];
#pragma unroll
            for (int i = 0; i < 4; ++i) {
                const int row = wm * 64 + i * 16 + ln;
                xf[i] = *(const half8*)&As[row][(((ks << 2) | lh) ^ (row & 7)) * 8];
            }
#pragma unroll
            for (int j = 0; j < 4; ++j) {
                const int row = wn * 64 + j * 16 + ln;
                wf[j] = *(const half8*)&Bs[row][(((ks << 2) | lh) ^ (row & 7)) * 8];
            }
            if (vmode) {
#pragma unroll
                for (int i = 0; i < 4; ++i)
#pragma unroll
                    for (int j = 0; j < 4; ++j)
                        acc[i][j] = __builtin_amdgcn_mfma_f32_16x16x32_f16(xf[i], wf[j], acc[i][j], 0, 0, 0);
            } else {
#pragma unroll
                for (int i = 0; i < 4; ++i)
#pragma unroll
                    for (int j = 0; j < 4; ++j)
                        acc[i][j] = __builtin_amdgcn_mfma_f32_16x16x32_f16(wf[j], xf[i], acc[i][j], 0, 0, 0);
            }
        }
    }

    if (MODE == 0) {
        // transposed: D rows = feature (lh*4+p), cols = token (ln)
#pragma unroll
        for (int j = 0; j < 4; ++j) {
            const int fb = n0 + wn * 64 + j * 16 + lh * 4;
            const float4 b4 = *(const float4*)&bias[fb];
#pragma unroll
            for (int i = 0; i < 4; ++i) {
                const int tok = m0 + wm * 64 + i * 16 + ln;
                float4 v;
                v.x = acc[i][j][0] + b4.x;
                v.y = acc[i][j][1] + b4.y;
                v.z = acc[i][j][2] + b4.z;
                v.w = acc[i][j][3] + b4.w;
                *(float4*)&Cout[(size_t)tok * N + fb] = v;
            }
        }
    } else if (!vmode) {
        // Q/K transposed: feature n = n0+wn*64+j*16+lh*4+p (d consecutive in p)
        const float scl = (c == 0) ? QSCL : 1.0f;
        u16* dst = (c == 0) ? Qo : Ko;
#pragma unroll
        for (int j = 0; j < 4; ++j) {
            const int nb = n0 + wn * 64 + j * 16 + lh * 4;
            const float4 b4 = *(const float4*)&bias[nb];
            const int h  = (nb >> 6) & 15;
            const int d0 = nb & 63;
#pragma unroll
            for (int i = 0; i < 4; ++i) {
                const int tok = m0 + wm * 64 + i * 16 + ln;
                const int t = tok >> 1, b = tok & 1;
                uint2 pk;
                pk.x = pkrtz((acc[i][j][0] + b4.x) * scl, (acc[i][j][1] + b4.y) * scl);
                pk.y = pkrtz((acc[i][j][2] + b4.z) * scl, (acc[i][j][3] + b4.w) * scl);
                *(uint2*)&dst[(((size_t)b * NHEAD + h) * TSEQ + t) * DHEAD + d0] = pk;
            }
        }
    } else {
        // V normal: D rows = token (lh*4+p), cols = feature (ln).
        // store V^T [b][h][d][t]: pack (p0,p2)->b=0 t0..t0+1, (p1,p3)->b=1.
#pragma unroll
        for (int j = 0; j < 4; ++j) {
            const int col = n0 + wn * 64 + j * 16 + ln;
            const float bc = bias[col];
            const int h = (col >> 6) & 15;
            const int d = col & 63;
#pragma unroll
            for (int i = 0; i < 4; ++i) {
                const int mb = m0 + wm * 64 + i * 16 + lh * 4;
                const int t0 = mb >> 1;
                const float v0 = acc[i][j][0] + bc;
                const float v1 = acc[i][j][1] + bc;
                const float v2 = acc[i][j][2] + bc;
                const float v3 = acc[i][j][3] + bc;
                const u32 e0 = pkrtz(v0, v2);   // b=0: t0, t0+1
                const u32 e1 = pkrtz(v1, v3);   // b=1: t0, t0+1
                *(u32*)&Vo[(((size_t)0 * NHEAD + h) * DHEAD + d) * TSEQ + t0] = e0;
                *(u32*)&Vo[(((size_t)1 * NHEAD + h) * DHEAD + d) * TSEQ + t0] = e1;
            }
        }
    }
}

// ---------------------------------------------------------------------------
// S^T-formulation MFMA flash attention.
// Q pre-scaled by 8*log2e (exp2-domain). V^T in global [b][h][d][t].
// S^T = mfma(K_frag, Q_frag): lane owns ONE q-row (q = qr0+ln); its 16
// key-values per 16-key group live at key = 16j + 4*lh + r. Softmax stats
// per-lane + 2 cross-lh shuffles. P packed to LDS via pkrtz (b64 writes);
// PV via standard b128 frags. Paired q-tiles {p, 31-p}; reg-prefetch.
// ---------------------------------------------------------------------------
__global__ __launch_bounds__(256)
void flash_f16(const u16* __restrict__ Q, const u16* __restrict__ K,
               const u16* __restrict__ Vt, u16* __restrict__ AV,
               const int* __restrict__ causal_p)
{
    __shared__ __align__(16) u16 Qs[64][72];
    __shared__ __align__(16) u16 Ks[64][72];
    __shared__ __align__(16) u16 Vs[64][72];   // V^T tile: rows d, cols key
    __shared__ __align__(16) u16 Ps[64][72];   // P: rows q, cols key

    const int tid  = threadIdx.x;
    const int lane = tid & 63;
    const int wv   = tid >> 6;
    const int ln   = lane & 15, lh = lane >> 4;
    const int bh   = blockIdx.x;                // b*16 + h
    const int pr   = blockIdx.y;                // 0..15
    const int b    = bh >> 4;
    const int h    = bh & 15;
    const int causal = causal_p[0];

    const u16* Qg = Q  + (size_t)bh * TSEQ * DHEAD;
    const u16* Kg = K  + (size_t)bh * TSEQ * DHEAD;
    const u16* Vg = Vt + (size_t)bh * DHEAD * TSEQ;

    const int lrow = tid >> 3;                  // 0..31
    const int lc8  = (tid & 7) * 8;

    for (int hf = 0; hf < 2; ++hf) {
        const int qb     = hf ? (NQB - 1 - pr) : pr;
        const int kb_end = causal ? qb : (NQB - 1);

        __syncthreads();     // prior tile's LDS fully consumed

        // Q tile -> LDS; prefetch K/V^T block 0 into regs
        *(uint4*)&Qs[lrow][lc8]      = *(const uint4*)(Qg + (size_t)(qb * 64 + lrow) * DHEAD + lc8);
        *(uint4*)&Qs[lrow + 32][lc8] = *(const uint4*)(Qg + (size_t)(qb * 64 + lrow + 32) * DHEAD + lc8);
        uint4 kreg0 = *(const uint4*)(Kg + (size_t)lrow * DHEAD + lc8);
        uint4 kreg1 = *(const uint4*)(Kg + (size_t)(lrow + 32) * DHEAD + lc8);
        uint4 vreg0 = *(const uint4*)(Vg + (size_t)lrow * TSEQ + lc8);
        uint4 vreg1 = *(const uint4*)(Vg + (size_t)(lrow + 32) * TSEQ + lc8);
        __syncthreads();

        const int qr0  = wv * 16;
        const int qloc = qr0 + ln;              // this lane's q-row
        const half8 bQ0 = *(const half8*)&Qs[qloc][lh * 8];
        const half8 bQ1 = *(const half8*)&Qs[qloc][32 + lh * 8];

        const floatx4 zero4 = {0.0f, 0.0f, 0.0f, 0.0f};
        floatx4 o[4];
#pragma unroll
        for (int j = 0; j < 4; ++j) o[j] = zero4;
        float m_i = -3.0e38f, l_i = 0.0f;

        for (int kb = 0; kb <= kb_end; ++kb) {
            // stage prefetched regs -> LDS (both straight copies now)
            *(uint4*)&Ks[lrow][lc8]      = kreg0;
            *(uint4*)&Ks[lrow + 32][lc8] = kreg1;
            *(uint4*)&Vs[lrow][lc8]      = vreg0;
            *(uint4*)&Vs[lrow + 32][lc8] = vreg1;
            __syncthreads();

            // prefetch next K/V^T block
            if (kb < kb_end) {
                const size_t nk = (size_t)(kb + 1) * 64;
                kreg0 = *(const uint4*)(Kg + (nk + lrow) * DHEAD + lc8);
                kreg1 = *(const uint4*)(Kg + (nk + lrow + 32) * DHEAD + lc8);
                vreg0 = *(const uint4*)(Vg + (size_t)lrow * TSEQ + nk + lc8);
                vreg1 = *(const uint4*)(Vg + (size_t)(lrow + 32) * TSEQ + nk + lc8);
            }

            // S^T = K Q^T : s[j][r] = S[key = 16j+4lh+r][q = qloc]
            floatx4 s[4];
#pragma unroll
            for (int j = 0; j < 4; ++j) {
                half8 aK0 = *(const half8*)&Ks[j * 16 + ln][lh * 8];
                half8 aK1 = *(const half8*)&Ks[j * 16 + ln][32 + lh * 8];
                floatx4 z = zero4;
                z = __builtin_amdgcn_mfma_f32_16x16x32_f16(aK0, bQ0, z, 0, 0, 0);
                z = __builtin_amdgcn_mfma_f32_16x16x32_f16(aK1, bQ1, z, 0, 0, 0);
                s[j] = z;
            }
            if ((causal != 0) && (kb == qb)) {
#pragma unroll
                for (int j = 0; j < 4; ++j)
#pragma unroll
                    for (int r = 0; r < 4; ++r)
                        if (j * 16 + lh * 4 + r > qloc) s[j][r] -= MSK;
            }

            // per-lane online softmax (one q-row per lane; reduce across lh)
            float mx = m_i;
#pragma unroll
            for (int j = 0; j < 4; ++j)
#pragma unroll
                for (int r = 0; r < 4; ++r) mx = fmaxf(mx, s[j][r]);
            mx = fmaxf(mx, __shfl_xor(mx, 16));
            mx = fmaxf(mx, __shfl_xor(mx, 32));
            const float alpha = exp2f(m_i - mx);
            m_i = mx;

            float p[4][4];
            float rs = 0.0f;
#pragma unroll
            for (int j = 0; j < 4; ++j)
#pragma unroll
                for (int r = 0; r < 4; ++r) {
                    p[j][r] = exp2f(s[j][r] - mx);
                    rs += p[j][r];
                }
            rs += __shfl_xor(rs, 16);
            rs += __shfl_xor(rs, 32);
            l_i = l_i * alpha + rs;

            // P -> LDS, packed b64 (rows wave-private; no barrier needed)
#pragma unroll
            for (int j = 0; j < 4; ++j) {
                uint2 pk;
                pk.x = pkrtz(p[j][0], p[j][1]);
                pk.y = pkrtz(p[j][2], p[j][3]);
                *(uint2*)&Ps[qloc][j * 16 + lh * 4] = pk;
            }

            // rescale o: o[j][r] belongs to q-row (lh*4+r); alpha lives in
            // lane ln' = lh*4+r (any lh-group; take group 0).
            float a_r[4];
#pragma unroll
            for (int r = 0; r < 4; ++r) a_r[r] = __shfl(alpha, ((lane >> 4) << 2) + r);
#pragma unroll
            for (int j = 0; j < 4; ++j)
#pragma unroll
                for (int r = 0; r < 4; ++r) o[j][r] *= a_r[r];

            // O += P V : a = P rows (q), b = V^T rows (d)
            half8 aP0 = *(const half8*)&Ps[qloc][lh * 8];
            half8 aP1 = *(const half8*)&Ps[qloc][32 + lh * 8];
#pragma unroll
            for (int j = 0; j < 4; ++j) {
                half8 bV0 = *(const half8*)&Vs[j * 16 + ln][lh * 8];
                half8 bV1 = *(const half8*)&Vs[j * 16 + ln][32 + lh * 8];
                o[j] = __builtin_amdgcn_mfma_f32_16x16x32_f16(aP0, bV0, o[j], 0, 0, 0);
                o[j] = __builtin_amdgcn_mfma_f32_16x16x32_f16(aP1, bV1, o[j], 0, 0, 0);
            }
            __syncthreads();   // all reads of Ks/Vs done before next staging
        }

        // epilogue: o rows = q-local lh*4+r, cols d = 16j+ln
#pragma unroll
        for (int r = 0; r < 4; ++r) {
            const float lr = __shfl(l_i, ((lane >> 4) << 2) + r);
            const float il = 1.0f / lr;
            const int qrow = qb * 64 + qr0 + lh * 4 + r;
#pragma unroll
            for (int j = 0; j < 4; ++j) {
                const int d = j * 16 + ln;
                AV[((size_t)qrow * BB + b) * DMODEL + h * 64 + d] = f2h(o[j][r] * il);
            }
        }
    }
}

// ---------------------------------------------------------------------------
extern "C" void kernel_launch(void* const* d_in, const int* in_sizes, int n_in,
                              void* d_out, int out_size, void* d_ws, size_t ws_size,
                              hipStream_t stream)
{
    const float* x      = (const float*)d_in[0];
    const float* qkv_w  = (const float*)d_in[1];
    const float* qkv_b  = (const float*)d_in[2];
    const float* out_w  = (const float*)d_in[3];
    const float* out_b  = (const float*)d_in[4];
    const int*   is_causal = (const int*)d_in[5];
    float* out = (float*)d_out;

    u16* ws   = (u16*)d_ws;
    u16* xb   = ws;                       // 4096*1024
    u16* wqkv = xb   + (size_t)4194304;   // 3072*1024
    u16* wout = wqkv + (size_t)3145728;   // 1024*1024
    u16* Qh   = wout + (size_t)1048576;   // [b][h][t][d]
    u16* Kh   = Qh   + (size_t)4194304;   // [b][h][t][d]
    u16* Vth  = Kh   + (size_t)4194304;   // [b][h][d][t]
    u16* AVh  = Vth  + (size_t)4194304;   // 4096*1024

    cast3_f32_f16<<<8192, 256, 0, stream>>>(x, xb, qkv_w, wqkv, out_w, wout);

    // QKV projection: M=4096, N=3072, K=1024 (Q scaled, V transposed)
    gemm_f16<1><<<dim3(3 * DMODEL / 128, MROWS / 128), 256, 0, stream>>>(
        xb, wqkv, qkv_b, nullptr, Qh, Kh, Vth, MROWS, 3 * DMODEL, DMODEL);

    // flash attention: grid (B*H, NQB/2) paired q-tiles
    flash_f16<<<dim3(BB * NHEAD, NQB / 2), 256, 0, stream>>>(
        Qh, Kh, Vth, AVh, is_causal);

    // output projection: M=4096, N=1024, K=1024 (fp32 out, float4 stores)
    gemm_f16<0><<<dim3(DMODEL / 128, MROWS / 128), 256, 0, stream>>>(
        AVh, wout, out_b, out, nullptr, nullptr, nullptr, MROWS, DMODEL, DMODEL);
}

// Round 7
// 209.612 us; speedup vs baseline: 1.1360x; 1.1360x over previous
//
#include <hip/hip_runtime.h>
#include <math.h>

#define TSEQ   2048
#define BB     2
#define DMODEL 1024
#define NHEAD  16
#define DHEAD  64
#define MROWS  (TSEQ * BB)   // 4096

typedef __attribute__((ext_vector_type(8))) _Float16 half8;
typedef __attribute__((ext_vector_type(4))) float    floatx4;
typedef unsigned short u16;
typedef unsigned int   u32;

#define QSCL 11.5415603f   /* 8 * log2(e): Q pre-scale -> exp2-domain scores */
#define MSK  1442695.0f    /* 1e6 * log2(e) */

__device__ __forceinline__ u16 f2h(float f) {
    union { _Float16 h; u16 u; } cv;
    cv.h = (_Float16)f;
    return cv.u;
}

// packed fp32x2 -> fp16x2 (round-to-zero) as u32
__device__ __forceinline__ u32 pkrtz(float a, float b) {
    typedef __attribute__((ext_vector_type(2))) __fp16 fp16x2;
    union { fp16x2 h; u32 u; } cv;
    cv.h = __builtin_amdgcn_cvt_pkrtz(a, b);
    return cv.u;
}

__device__ __forceinline__ void async_cp16(const u16* g, u16* l) {
    __builtin_amdgcn_global_load_lds(
        (const __attribute__((address_space(1))) unsigned int*)g,
        (__attribute__((address_space(3))) unsigned int*)l, 16, 0, 0);
}

// ---------------------------------------------------------------------------
// one-launch fp32 -> fp16 cast of x, qkv_w, out_w
// float4 units: x 1048576, qkv_w 786432, out_w 262144 (total 2097152)
// ---------------------------------------------------------------------------
__global__ __launch_bounds__(256)
void cast3_f32_f16(const float* __restrict__ a, u16* __restrict__ oa,
                   const float* __restrict__ b, u16* __restrict__ ob,
                   const float* __restrict__ c, u16* __restrict__ oc)
{
    int i = blockIdx.x * 256 + threadIdx.x;
    const float* src; u16* dst; int off;
    if (i < 1048576)      { src = a; dst = oa; off = 0; }
    else if (i < 1835008) { src = b; dst = ob; off = 1048576; }
    else                  { src = c; dst = oc; off = 1835008; }
    int j = i - off;
    float4 v = ((const float4*)src)[j];
    ushort4 o;
    o.x = f2h(v.x); o.y = f2h(v.y); o.z = f2h(v.z); o.w = f2h(v.w);
    ((ushort4*)dst)[j] = o;
}

// ---------------------------------------------------------------------------
// fp16 MFMA GEMM: C[M][N] = A[M][K]*W[N][K]^T + bias[N]
// 128(M) x 64(N) tile, BK=64, global_load_lds + XOR-swizzled LDS.
// 4 waves stacked in M (wave tile 32x64, acc 2x4). High TLP: 24.6 KB LDS,
// ~5-6 blocks/CU -> barrier drains overlapped across blocks.
// MODE 0 (out-proj): transposed orientation -> float4 stores.
// MODE 1 (QKV): c<2 (Q,K): transposed, packed uint2 fp16 -> [b][h][t][d],
//               Q scaled by QSCL;  c==2 (V): normal -> V^T [b][h][d][t].
// ---------------------------------------------------------------------------
template <int MODE>
__global__ __launch_bounds__(256)
void gemm_f16(const u16* __restrict__ A, const u16* __restrict__ W,
              const float* __restrict__ bias, float* __restrict__ Cout,
              u16* __restrict__ Qo, u16* __restrict__ Ko, u16* __restrict__ Vo,
              int M, int N, int K)
{
    __shared__ __align__(16) u16 As[128][64];
    __shared__ __align__(16) u16 Bs[64][64];

    const int tid  = threadIdx.x;
    const int lane = tid & 63;
    const int wv   = tid >> 6;
    const int ln   = lane & 15, lh = lane >> 4;
    const int m0   = blockIdx.y * 128;
    const int n0   = blockIdx.x * 64;

    const int c = (MODE == 1) ? (n0 >> 10) : 0;    // block-uniform
    const bool vmode = (MODE == 1) && (c == 2);    // normal orientation

    const int srowA = wv * 32 + (lane >> 3);       // + t*8, t=0..3
    const int srowW = wv * 16 + (lane >> 3);       // + t*8, t=0..1
    const int sslot = lane & 7;

    const floatx4 zero4 = {0.0f, 0.0f, 0.0f, 0.0f};
    floatx4 acc[2][4];
#pragma unroll
    for (int i = 0; i < 2; ++i)
#pragma unroll
        for (int j = 0; j < 4; ++j) acc[i][j] = zero4;

    for (int k0 = 0; k0 < K; k0 += 64) {
        __syncthreads();
#pragma unroll
        for (int t = 0; t < 4; ++t) {
            const int row = srowA + t * 8;
            const int g   = sslot ^ (row & 7);
            async_cp16(A + (size_t)(m0 + row) * K + k0 + g * 8, &As[row][sslot * 8]);
        }
#pragma unroll
        for (int t = 0; t < 2; ++t) {
            const int row = srowW + t * 8;
            const int g   = sslot ^ (row & 7);
            async_cp16(W + (size_t)(n0 + row) * K + k0 + g * 8, &Bs[row][sslot * 8]);
        }
        __syncthreads();

#pragma unroll
        for (int ks = 0; ks < 2; ++ks) {
            half8 xf[2], wf[4];
#pragma unroll
            for (int i = 0; i < 2; ++i) {
                const int row = wv * 32 + i * 16 + ln;
                xf[i] = *(const half8*)&As[row][(((ks << 2) | lh) ^ (row & 7)) * 8];
            }
#pragma unroll
            for (int j = 0; j < 4; ++j) {
                const int row = j * 16 + ln;
                wf[j] = *(const half8*)&Bs[row][(((ks << 2) | lh) ^ (row & 7)) * 8];
            }
            if (vmode) {
#pragma unroll
                for (int i = 0; i < 2; ++i)
#pragma unroll
                    for (int j = 0; j < 4; ++j)
                        acc[i][j] = __builtin_amdgcn_mfma_f32_16x16x32_f16(xf[i], wf[j], acc[i][j], 0, 0, 0);
            } else {
#pragma unroll
                for (int i = 0; i < 2; ++i)
#pragma unroll
                    for (int j = 0; j < 4; ++j)
                        acc[i][j] = __builtin_amdgcn_mfma_f32_16x16x32_f16(wf[j], xf[i], acc[i][j], 0, 0, 0);
            }
        }
    }

    if (MODE == 0) {
        // transposed: D rows = feature (lh*4+p), cols = token (ln)
#pragma unroll
        for (int j = 0; j < 4; ++j) {
            const int fb = n0 + j * 16 + lh * 4;
            const float4 b4 = *(const float4*)&bias[fb];
#pragma unroll
            for (int i = 0; i < 2; ++i) {
                const int tok = m0 + wv * 32 + i * 16 + ln;
                float4 v;
                v.x = acc[i][j][0] + b4.x;
                v.y = acc[i][j][1] + b4.y;
                v.z = acc[i][j][2] + b4.z;
                v.w = acc[i][j][3] + b4.w;
                *(float4*)&Cout[(size_t)tok * N + fb] = v;
            }
        }
    } else if (!vmode) {
        // Q/K transposed: feature nb..nb+3 consecutive in acc regs
        const float scl = (c == 0) ? QSCL : 1.0f;
        u16* dst = (c == 0) ? Qo : Ko;
#pragma unroll
        for (int j = 0; j < 4; ++j) {
            const int nb = n0 + j * 16 + lh * 4;
            const float4 b4 = *(const float4*)&bias[nb];
            const int h  = (nb >> 6) & 15;
            const int d0 = nb & 63;
#pragma unroll
            for (int i = 0; i < 2; ++i) {
                const int tok = m0 + wv * 32 + i * 16 + ln;
                const int t = tok >> 1, b = tok & 1;
                uint2 pk;
                pk.x = pkrtz((acc[i][j][0] + b4.x) * scl, (acc[i][j][1] + b4.y) * scl);
                pk.y = pkrtz((acc[i][j][2] + b4.z) * scl, (acc[i][j][3] + b4.w) * scl);
                *(uint2*)&dst[(((size_t)b * NHEAD + h) * TSEQ + t) * DHEAD + d0] = pk;
            }
        }
    } else {
        // V normal: rows = token (lh*4+p), cols = feature (ln) -> V^T stores
#pragma unroll
        for (int j = 0; j < 4; ++j) {
            const int col = n0 + j * 16 + ln;
            const float bc = bias[col];
            const int h = (col >> 6) & 15;
            const int d = col & 63;
#pragma unroll
            for (int i = 0; i < 2; ++i) {
                const int mb = m0 + wv * 32 + i * 16 + lh * 4;
                const int t0 = mb >> 1;
                const u32 e0 = pkrtz(acc[i][j][0] + bc, acc[i][j][2] + bc);  // b=0
                const u32 e1 = pkrtz(acc[i][j][1] + bc, acc[i][j][3] + bc);  // b=1
                *(u32*)&Vo[(((size_t)0 * NHEAD + h) * DHEAD + d) * TSEQ + t0] = e0;
                *(u32*)&Vo[(((size_t)1 * NHEAD + h) * DHEAD + d) * TSEQ + t0] = e1;
            }
        }
    }
}

// ---------------------------------------------------------------------------
// S^T-formulation MFMA flash attention, 128-q-row tiles.
// 4 waves x 32 q-rows: K/V LDS reads amortized over 2x MFMA vs 16-row waves.
// Q pre-scaled by 8*log2e; V^T [b][h][d][t]. Lane owns one q-row per
// 16-row subtile; softmax per-lane + 2 cross-lh shuffles.
// Block mapping pairs {qt, 15-qt} across the two grid halves so each CU's
// two resident blocks sum to constant causal work (round-robin heuristic).
// ---------------------------------------------------------------------------
__global__ __launch_bounds__(256)
void flash_f16(const u16* __restrict__ Q, const u16* __restrict__ K,
               const u16* __restrict__ Vt, u16* __restrict__ AV,
               const int* __restrict__ causal_p)
{
    __shared__ __align__(16) u16 Qs[128][72];
    __shared__ __align__(16) u16 Ps[128][72];
    __shared__ __align__(16) u16 Ks[64][72];
    __shared__ __align__(16) u16 Vs[64][72];

    const int tid  = threadIdx.x;
    const int lane = tid & 63;
    const int wv   = tid >> 6;
    const int ln   = lane & 15, lh = lane >> 4;

    const int bidx = blockIdx.x;               // 0..511
    const int cc   = bidx & 255;
    const int hf   = bidx >> 8;
    const int bh   = cc & 31;                  // b*16 + h
    const int pr   = cc >> 5;                  // 0..7
    const int qt   = hf ? (15 - pr) : pr;      // q-tile (128 rows)
    const int b    = bh >> 4;
    const int h    = bh & 15;
    const int causal = causal_p[0];

    const u16* Qg = Q  + (size_t)bh * TSEQ * DHEAD;
    const u16* Kg = K  + (size_t)bh * TSEQ * DHEAD;
    const u16* Vg = Vt + (size_t)bh * DHEAD * TSEQ;

    const int lrow = tid >> 3;                 // 0..31
    const int lc8  = (tid & 7) * 8;

    // Q tile 128x64 -> LDS; prefetch K/V^T block 0
#pragma unroll
    for (int t = 0; t < 4; ++t)
        *(uint4*)&Qs[lrow + t * 32][lc8] =
            *(const uint4*)(Qg + (size_t)(qt * 128 + lrow + t * 32) * DHEAD + lc8);
    uint4 kreg0 = *(const uint4*)(Kg + (size_t)lrow * DHEAD + lc8);
    uint4 kreg1 = *(const uint4*)(Kg + (size_t)(lrow + 32) * DHEAD + lc8);
    uint4 vreg0 = *(const uint4*)(Vg + (size_t)lrow * TSEQ + lc8);
    uint4 vreg1 = *(const uint4*)(Vg + (size_t)(lrow + 32) * TSEQ + lc8);
    __syncthreads();

    const int qr0 = wv * 32;
    half8 bQ[2][2];
#pragma unroll
    for (int s = 0; s < 2; ++s)
#pragma unroll
        for (int ks = 0; ks < 2; ++ks)
            bQ[s][ks] = *(const half8*)&Qs[qr0 + s * 16 + ln][ks * 32 + lh * 8];

    const floatx4 zero4 = {0.0f, 0.0f, 0.0f, 0.0f};
    floatx4 o[2][4];
#pragma unroll
    for (int s = 0; s < 2; ++s)
#pragma unroll
        for (int j = 0; j < 4; ++j) o[s][j] = zero4;
    float m_i[2] = {-3.0e38f, -3.0e38f};
    float l_i[2] = {0.0f, 0.0f};

    const int kb_end = causal ? (2 * qt + 1) : (TSEQ / 64 - 1);
    for (int kb = 0; kb <= kb_end; ++kb) {
        // stage prefetched regs -> LDS
        *(uint4*)&Ks[lrow][lc8]      = kreg0;
        *(uint4*)&Ks[lrow + 32][lc8] = kreg1;
        *(uint4*)&Vs[lrow][lc8]      = vreg0;
        *(uint4*)&Vs[lrow + 32][lc8] = vreg1;
        __syncthreads();

        if (kb < kb_end) {
            const size_t nk = (size_t)(kb + 1) * 64;
            kreg0 = *(const uint4*)(Kg + (nk + lrow) * DHEAD + lc8);
            kreg1 = *(const uint4*)(Kg + (nk + lrow + 32) * DHEAD + lc8);
            vreg0 = *(const uint4*)(Vg + (size_t)lrow * TSEQ + nk + lc8);
            vreg1 = *(const uint4*)(Vg + (size_t)(lrow + 32) * TSEQ + nk + lc8);
        }

        // wave-uniform skip: all this wave's q-rows < every key in block
        const bool active = !causal || (kb * 64 <= qt * 128 + qr0 + 31);
        if (active) {
            // S^T: st[s][j][r] = S[key=64kb+16j+4lh+r][q=qt*128+qr0+16s+ln]
            floatx4 st[2][4];
#pragma unroll
            for (int j = 0; j < 4; ++j) {
                half8 aK0 = *(const half8*)&Ks[j * 16 + ln][lh * 8];
                half8 aK1 = *(const half8*)&Ks[j * 16 + ln][32 + lh * 8];
#pragma unroll
                for (int s = 0; s < 2; ++s) {
                    floatx4 z = zero4;
                    z = __builtin_amdgcn_mfma_f32_16x16x32_f16(aK0, bQ[s][0], z, 0, 0, 0);
                    z = __builtin_amdgcn_mfma_f32_16x16x32_f16(aK1, bQ[s][1], z, 0, 0, 0);
                    st[s][j] = z;
                }
            }
            if (causal && (kb * 64 + 63 > qt * 128 + qr0)) {
#pragma unroll
                for (int s = 0; s < 2; ++s) {
                    const int qg = qt * 128 + qr0 + s * 16 + ln;
#pragma unroll
                    for (int j = 0; j < 4; ++j)
#pragma unroll
                        for (int r = 0; r < 4; ++r)
                            if (kb * 64 + j * 16 + lh * 4 + r > qg) st[s][j][r] -= MSK;
                }
            }

            float p[2][4][4];
#pragma unroll
            for (int s = 0; s < 2; ++s) {
                float mx = m_i[s];
#pragma unroll
                for (int j = 0; j < 4; ++j)
#pragma unroll
                    for (int r = 0; r < 4; ++r) mx = fmaxf(mx, st[s][j][r]);
                mx = fmaxf(mx, __shfl_xor(mx, 16));
                mx = fmaxf(mx, __shfl_xor(mx, 32));
                const float alpha = exp2f(m_i[s] - mx);
                m_i[s] = mx;

                float rs = 0.0f;
#pragma unroll
                for (int j = 0; j < 4; ++j)
#pragma unroll
                    for (int r = 0; r < 4; ++r) {
                        p[s][j][r] = exp2f(st[s][j][r] - mx);
                        rs += p[s][j][r];
                    }
                rs += __shfl_xor(rs, 16);
                rs += __shfl_xor(rs, 32);
                l_i[s] = l_i[s] * alpha + rs;

                // P -> LDS packed (wave-private rows; no barrier needed)
#pragma unroll
                for (int j = 0; j < 4; ++j) {
                    uint2 pk;
                    pk.x = pkrtz(p[s][j][0], p[s][j][1]);
                    pk.y = pkrtz(p[s][j][2], p[s][j][3]);
                    *(uint2*)&Ps[qr0 + s * 16 + ln][j * 16 + lh * 4] = pk;
                }

                // rescale o: o[s][j][r] is q-row 4lh+r of subtile s
                float a_r[4];
#pragma unroll
                for (int r = 0; r < 4; ++r) a_r[r] = __shfl(alpha, lh * 4 + r);
#pragma unroll
                for (int j = 0; j < 4; ++j)
#pragma unroll
                    for (int r = 0; r < 4; ++r) o[s][j][r] *= a_r[r];
            }

            // O += P V
            half8 aP[2][2];
#pragma unroll
            for (int s = 0; s < 2; ++s)
#pragma unroll
                for (int ks = 0; ks < 2; ++ks)
                    aP[s][ks] = *(const half8*)&Ps[qr0 + s * 16 + ln][ks * 32 + lh * 8];
#pragma unroll
            for (int j = 0; j < 4; ++j) {
                half8 bV0 = *(const half8*)&Vs[j * 16 + ln][lh * 8];
                half8 bV1 = *(const half8*)&Vs[j * 16 + ln][32 + lh * 8];
#pragma unroll
                for (int s = 0; s < 2; ++s) {
                    o[s][j] = __builtin_amdgcn_mfma_f32_16x16x32_f16(aP[s][0], bV0, o[s][j], 0, 0, 0);
                    o[s][j] = __builtin_amdgcn_mfma_f32_16x16x32_f16(aP[s][1], bV1, o[s][j], 0, 0, 0);
                }
            }
        }
        __syncthreads();   // all reads of Ks/Vs done before next staging
    }

    // epilogue: o[s][j][r] -> q = qt*128 + qr0 + 16s + 4lh + r, d = 16j + ln
#pragma unroll
    for (int s = 0; s < 2; ++s)
#pragma unroll
        for (int r = 0; r < 4; ++r) {
            const float lr = __shfl(l_i[s], lh * 4 + r);
            const float il = 1.0f / lr;
            const int q = qt * 128 + qr0 + s * 16 + lh * 4 + r;
#pragma unroll
            for (int j = 0; j < 4; ++j) {
                const int d = j * 16 + ln;
                AV[((size_t)q * BB + b) * DMODEL + h * 64 + d] = f2h(o[s][j][r] * il);
            }
        }
}

// ---------------------------------------------------------------------------
extern "C" void kernel_launch(void* const* d_in, const int* in_sizes, int n_in,
                              void* d_out, int out_size, void* d_ws, size_t ws_size,
                              hipStream_t stream)
{
    const float* x      = (const float*)d_in[0];
    const float* qkv_w  = (const float*)d_in[1];
    const float* qkv_b  = (const float*)d_in[2];
    const float* out_w  = (const float*)d_in[3];
    const float* out_b  = (const float*)d_in[4];
    const int*   is_causal = (const int*)d_in[5];
    float* out = (float*)d_out;

    u16* ws   = (u16*)d_ws;
    u16* xb   = ws;                       // 4096*1024
    u16* wqkv = xb   + (size_t)4194304;   // 3072*1024
    u16* wout = wqkv + (size_t)3145728;   // 1024*1024
    u16* Qh   = wout + (size_t)1048576;   // [b][h][t][d]
    u16* Kh   = Qh   + (size_t)4194304;   // [b][h][t][d]
    u16* Vth  = Kh   + (size_t)4194304;   // [b][h][d][t]
    u16* AVh  = Vth  + (size_t)4194304;   // 4096*1024

    cast3_f32_f16<<<8192, 256, 0, stream>>>(x, xb, qkv_w, wqkv, out_w, wout);

    // QKV projection: M=4096, N=3072, K=1024 (Q scaled, V transposed)
    gemm_f16<1><<<dim3(3 * DMODEL / 64, MROWS / 128), 256, 0, stream>>>(
        xb, wqkv, qkv_b, nullptr, Qh, Kh, Vth, MROWS, 3 * DMODEL, DMODEL);

    // flash attention: 512 blocks, one 128-row q-tile each
    flash_f16<<<512, 256, 0, stream>>>(Qh, Kh, Vth, AVh, is_causal);

    // output projection: M=4096, N=1024, K=1024 (fp32 out)
    gemm_f16<0><<<dim3(DMODEL / 64, MROWS / 128), 256, 0, stream>>>(
        AVh, wout, out_b, out, nullptr, nullptr, nullptr, MROWS, DMODEL, DMODEL);
}

// Round 8
// 195.314 us; speedup vs baseline: 1.2192x; 1.0732x over previous
//
#include <hip/hip_runtime.h>
#include <math.h>

#define TSEQ   2048
#define BB     2
#define DMODEL 1024
#define NHEAD  16
#define DHEAD  64
#define MROWS  (TSEQ * BB)   // 4096
#define NQB    (TSEQ / 64)   // 32 query tiles per (b,h)

typedef __attribute__((ext_vector_type(8))) _Float16 half8;
typedef __attribute__((ext_vector_type(4))) float    floatx4;
typedef unsigned short u16;
typedef unsigned int   u32;

#define QSCL 11.5415603f   /* 8 * log2(e): Q pre-scale -> exp2-domain scores */
#define MSK  1442695.0f    /* 1e6 * log2(e) */

__device__ __forceinline__ u16 f2h(float f) {
    union { _Float16 h; u16 u; } cv;
    cv.h = (_Float16)f;
    return cv.u;
}

// packed fp32x2 -> fp16x2 (round-to-zero) as u32
__device__ __forceinline__ u32 pkrtz(float a, float b) {
    typedef __attribute__((ext_vector_type(2))) __fp16 fp16x2;
    union { fp16x2 h; u32 u; } cv;
    cv.h = __builtin_amdgcn_cvt_pkrtz(a, b);
    return cv.u;
}

__device__ __forceinline__ void async_cp16(const u16* g, u16* l) {
    __builtin_amdgcn_global_load_lds(
        (const __attribute__((address_space(1))) unsigned int*)g,
        (__attribute__((address_space(3))) unsigned int*)l, 16, 0, 0);
}

// ---------------------------------------------------------------------------
// one-launch fp32 -> fp16 cast of x, qkv_w, out_w
// float4 units: x 1048576, qkv_w 786432, out_w 262144 (total 2097152)
// ---------------------------------------------------------------------------
__global__ __launch_bounds__(256)
void cast3_f32_f16(const float* __restrict__ a, u16* __restrict__ oa,
                   const float* __restrict__ b, u16* __restrict__ ob,
                   const float* __restrict__ c, u16* __restrict__ oc)
{
    int i = blockIdx.x * 256 + threadIdx.x;
    const float* src; u16* dst; int off;
    if (i < 1048576)      { src = a; dst = oa; off = 0; }
    else if (i < 1835008) { src = b; dst = ob; off = 1048576; }
    else                  { src = c; dst = oc; off = 1835008; }
    int j = i - off;
    float4 v = ((const float4*)src)[j];
    ushort4 o;
    o.x = f2h(v.x); o.y = f2h(v.y); o.z = f2h(v.z); o.w = f2h(v.w);
    ((ushort4*)dst)[j] = o;
}

// ---------------------------------------------------------------------------
// fp16 MFMA GEMM: C[M][N] = A[M][K]*W[N][K]^T + bias[N]
// 128(M) x 64(N) tile, BK=64, global_load_lds + XOR-swizzled LDS.
// MODE 0 (out-proj): transposed orientation -> float4 stores.
// MODE 1 (QKV): c<2 (Q,K): transposed, packed uint2 fp16 -> [b][h][t][d],
//               Q scaled by QSCL;  c==2 (V): normal -> V^T [b][h][d][t].
// ---------------------------------------------------------------------------
template <int MODE>
__global__ __launch_bounds__(256)
void gemm_f16(const u16* __restrict__ A, const u16* __restrict__ W,
              const float* __restrict__ bias, float* __restrict__ Cout,
              u16* __restrict__ Qo, u16* __restrict__ Ko, u16* __restrict__ Vo,
              int M, int N, int K)
{
    __shared__ __align__(16) u16 As[128][64];
    __shared__ __align__(16) u16 Bs[64][64];

    const int tid  = threadIdx.x;
    const int lane = tid & 63;
    const int wv   = tid >> 6;
    const int ln   = lane & 15, lh = lane >> 4;
    const int m0   = blockIdx.y * 128;
    const int n0   = blockIdx.x * 64;

    const int c = (MODE == 1) ? (n0 >> 10) : 0;    // block-uniform
    const bool vmode = (MODE == 1) && (c == 2);    // normal orientation

    const int srowA = wv * 32 + (lane >> 3);       // + t*8, t=0..3
    const int srowW = wv * 16 + (lane >> 3);       // + t*8, t=0..1
    const int sslot = lane & 7;

    const floatx4 zero4 = {0.0f, 0.0f, 0.0f, 0.0f};
    floatx4 acc[2][4];
#pragma unroll
    for (int i = 0; i < 2; ++i)
#pragma unroll
        for (int j = 0; j < 4; ++j) acc[i][j] = zero4;

    for (int k0 = 0; k0 < K; k0 += 64) {
        __syncthreads();
#pragma unroll
        for (int t = 0; t < 4; ++t) {
            const int row = srowA + t * 8;
            const int g   = sslot ^ (row & 7);
            async_cp16(A + (size_t)(m0 + row) * K + k0 + g * 8, &As[row][sslot * 8]);
        }
#pragma unroll
        for (int t = 0; t < 2; ++t) {
            const int row = srowW + t * 8;
            const int g   = sslot ^ (row & 7);
            async_cp16(W + (size_t)(n0 + row) * K + k0 + g * 8, &Bs[row][sslot * 8]);
        }
        __syncthreads();

#pragma unroll
        for (int ks = 0; ks < 2; ++ks) {
            half8 xf[2], wf[4];
#pragma unroll
            for (int i = 0; i < 2; ++i) {
                const int row = wv * 32 + i * 16 + ln;
                xf[i] = *(const half8*)&As[row][(((ks << 2) | lh) ^ (row & 7)) * 8];
            }
#pragma unroll
            for (int j = 0; j < 4; ++j) {
                const int row = j * 16 + ln;
                wf[j] = *(const half8*)&Bs[row][(((ks << 2) | lh) ^ (row & 7)) * 8];
            }
            if (vmode) {
#pragma unroll
                for (int i = 0; i < 2; ++i)
#pragma unroll
                    for (int j = 0; j < 4; ++j)
                        acc[i][j] = __builtin_amdgcn_mfma_f32_16x16x32_f16(xf[i], wf[j], acc[i][j], 0, 0, 0);
            } else {
#pragma unroll
                for (int i = 0; i < 2; ++i)
#pragma unroll
                    for (int j = 0; j < 4; ++j)
                        acc[i][j] = __builtin_amdgcn_mfma_f32_16x16x32_f16(wf[j], xf[i], acc[i][j], 0, 0, 0);
            }
        }
    }

    if (MODE == 0) {
        // transposed: D rows = feature (lh*4+p), cols = token (ln)
#pragma unroll
        for (int j = 0; j < 4; ++j) {
            const int fb = n0 + j * 16 + lh * 4;
            const float4 b4 = *(const float4*)&bias[fb];
#pragma unroll
            for (int i = 0; i < 2; ++i) {
                const int tok = m0 + wv * 32 + i * 16 + ln;
                float4 v;
                v.x = acc[i][j][0] + b4.x;
                v.y = acc[i][j][1] + b4.y;
                v.z = acc[i][j][2] + b4.z;
                v.w = acc[i][j][3] + b4.w;
                *(float4*)&Cout[(size_t)tok * N + fb] = v;
            }
        }
    } else if (!vmode) {
        // Q/K transposed: feature nb..nb+3 consecutive in acc regs
        const float scl = (c == 0) ? QSCL : 1.0f;
        u16* dst = (c == 0) ? Qo : Ko;
#pragma unroll
        for (int j = 0; j < 4; ++j) {
            const int nb = n0 + j * 16 + lh * 4;
            const float4 b4 = *(const float4*)&bias[nb];
            const int h  = (nb >> 6) & 15;
            const int d0 = nb & 63;
#pragma unroll
            for (int i = 0; i < 2; ++i) {
                const int tok = m0 + wv * 32 + i * 16 + ln;
                const int t = tok >> 1, b = tok & 1;
                uint2 pk;
                pk.x = pkrtz((acc[i][j][0] + b4.x) * scl, (acc[i][j][1] + b4.y) * scl);
                pk.y = pkrtz((acc[i][j][2] + b4.z) * scl, (acc[i][j][3] + b4.w) * scl);
                *(uint2*)&dst[(((size_t)b * NHEAD + h) * TSEQ + t) * DHEAD + d0] = pk;
            }
        }
    } else {
        // V normal: rows = token (lh*4+p), cols = feature (ln) -> V^T stores
#pragma unroll
        for (int j = 0; j < 4; ++j) {
            const int col = n0 + j * 16 + ln;
            const float bc = bias[col];
            const int h = (col >> 6) & 15;
            const int d = col & 63;
#pragma unroll
            for (int i = 0; i < 2; ++i) {
                const int mb = m0 + wv * 32 + i * 16 + lh * 4;
                const int t0 = mb >> 1;
                const u32 e0 = pkrtz(acc[i][j][0] + bc, acc[i][j][2] + bc);  // b=0
                const u32 e1 = pkrtz(acc[i][j][1] + bc, acc[i][j][3] + bc);  // b=1
                *(u32*)&Vo[(((size_t)0 * NHEAD + h) * DHEAD + d) * TSEQ + t0] = e0;
                *(u32*)&Vo[(((size_t)1 * NHEAD + h) * DHEAD + d) * TSEQ + t0] = e1;
            }
        }
    }
}

// ---------------------------------------------------------------------------
// S^T-formulation MFMA flash attention, 64-q-row tiles, ONE tile per block.
// Grid 1024 blocks -> 4 resident blocks/CU (LDS 36.9 KB), 4 waves/SIMD:
// latency chains (barrier->lgkm->MFMA->shuffle->exp2->pack) hidden by TLP.
// Causal balance: 4 dispatch phases map slot j to qb {31-j, j, 23-j, 8+j};
// any CU's 4 resident blocks sum to 66 iterations (constant), heavy first.
// Q pre-scaled by 8*log2e; V^T [b][h][d][t]; per-lane softmax + 2 shuffles.
// ---------------------------------------------------------------------------
__global__ __launch_bounds__(256)
void flash_f16(const u16* __restrict__ Q, const u16* __restrict__ K,
               const u16* __restrict__ Vt, u16* __restrict__ AV,
               const int* __restrict__ causal_p)
{
    __shared__ __align__(16) u16 Qs[64][72];
    __shared__ __align__(16) u16 Ks[64][72];
    __shared__ __align__(16) u16 Vs[64][72];   // V^T tile: rows d, cols key
    __shared__ __align__(16) u16 Ps[64][72];   // P: rows q, cols key

    const int tid  = threadIdx.x;
    const int lane = tid & 63;
    const int wv   = tid >> 6;
    const int ln   = lane & 15, lh = lane >> 4;

    const int phase = blockIdx.x >> 8;          // 0..3
    const int slot  = blockIdx.x & 255;
    const int bh    = slot & 31;                // b*16 + h
    const int jq    = slot >> 5;                // 0..7
    int qb;
    if      (phase == 0) qb = 31 - jq;
    else if (phase == 1) qb = jq;
    else if (phase == 2) qb = 23 - jq;
    else                 qb = 8 + jq;

    const int b = bh >> 4;
    const int h = bh & 15;
    const int causal = causal_p[0];

    const u16* Qg = Q  + (size_t)bh * TSEQ * DHEAD;
    const u16* Kg = K  + (size_t)bh * TSEQ * DHEAD;
    const u16* Vg = Vt + (size_t)bh * DHEAD * TSEQ;

    const int lrow = tid >> 3;                  // 0..31
    const int lc8  = (tid & 7) * 8;

    // Q tile -> LDS; prefetch K/V^T block 0 into regs
    *(uint4*)&Qs[lrow][lc8]      = *(const uint4*)(Qg + (size_t)(qb * 64 + lrow) * DHEAD + lc8);
    *(uint4*)&Qs[lrow + 32][lc8] = *(const uint4*)(Qg + (size_t)(qb * 64 + lrow + 32) * DHEAD + lc8);
    uint4 kreg0 = *(const uint4*)(Kg + (size_t)lrow * DHEAD + lc8);
    uint4 kreg1 = *(const uint4*)(Kg + (size_t)(lrow + 32) * DHEAD + lc8);
    uint4 vreg0 = *(const uint4*)(Vg + (size_t)lrow * TSEQ + lc8);
    uint4 vreg1 = *(const uint4*)(Vg + (size_t)(lrow + 32) * TSEQ + lc8);
    __syncthreads();

    const int qr0  = wv * 16;
    const int qloc = qr0 + ln;                  // this lane's q-row (local)
    const half8 bQ0 = *(const half8*)&Qs[qloc][lh * 8];
    const half8 bQ1 = *(const half8*)&Qs[qloc][32 + lh * 8];

    const floatx4 zero4 = {0.0f, 0.0f, 0.0f, 0.0f};
    floatx4 o[4];
#pragma unroll
    for (int j = 0; j < 4; ++j) o[j] = zero4;
    float m_i = -3.0e38f, l_i = 0.0f;

    const int kb_end = causal ? qb : (TSEQ / 64 - 1);
    for (int kb = 0; kb <= kb_end; ++kb) {
        // stage prefetched regs -> LDS (straight copies)
        *(uint4*)&Ks[lrow][lc8]      = kreg0;
        *(uint4*)&Ks[lrow + 32][lc8] = kreg1;
        *(uint4*)&Vs[lrow][lc8]      = vreg0;
        *(uint4*)&Vs[lrow + 32][lc8] = vreg1;
        __syncthreads();

        // prefetch next K/V^T block (hidden behind compute)
        if (kb < kb_end) {
            const size_t nk = (size_t)(kb + 1) * 64;
            kreg0 = *(const uint4*)(Kg + (nk + lrow) * DHEAD + lc8);
            kreg1 = *(const uint4*)(Kg + (nk + lrow + 32) * DHEAD + lc8);
            vreg0 = *(const uint4*)(Vg + (size_t)lrow * TSEQ + nk + lc8);
            vreg1 = *(const uint4*)(Vg + (size_t)(lrow + 32) * TSEQ + nk + lc8);
        }

        // S^T = K Q^T : s[j][r] = S[key = 16j+4lh+r][q = qloc]
        floatx4 s[4];
#pragma unroll
        for (int j = 0; j < 4; ++j) {
            half8 aK0 = *(const half8*)&Ks[j * 16 + ln][lh * 8];
            half8 aK1 = *(const half8*)&Ks[j * 16 + ln][32 + lh * 8];
            floatx4 z = zero4;
            z = __builtin_amdgcn_mfma_f32_16x16x32_f16(aK0, bQ0, z, 0, 0, 0);
            z = __builtin_amdgcn_mfma_f32_16x16x32_f16(aK1, bQ1, z, 0, 0, 0);
            s[j] = z;
        }
        if ((causal != 0) && (kb == qb)) {
#pragma unroll
            for (int j = 0; j < 4; ++j)
#pragma unroll
                for (int r = 0; r < 4; ++r)
                    if (j * 16 + lh * 4 + r > qloc) s[j][r] -= MSK;
        }

        // per-lane online softmax (one q-row per lane; reduce across lh)
        float mx = m_i;
#pragma unroll
        for (int j = 0; j < 4; ++j)
#pragma unroll
            for (int r = 0; r < 4; ++r) mx = fmaxf(mx, s[j][r]);
        mx = fmaxf(mx, __shfl_xor(mx, 16));
        mx = fmaxf(mx, __shfl_xor(mx, 32));
        const float alpha = exp2f(m_i - mx);
        m_i = mx;

        float p[4][4];
        float rs = 0.0f;
#pragma unroll
        for (int j = 0; j < 4; ++j)
#pragma unroll
            for (int r = 0; r < 4; ++r) {
                p[j][r] = exp2f(s[j][r] - mx);
                rs += p[j][r];
            }
        rs += __shfl_xor(rs, 16);
        rs += __shfl_xor(rs, 32);
        l_i = l_i * alpha + rs;

        // P -> LDS, packed b64 (rows wave-private; no barrier needed)
#pragma unroll
        for (int j = 0; j < 4; ++j) {
            uint2 pk;
            pk.x = pkrtz(p[j][0], p[j][1]);
            pk.y = pkrtz(p[j][2], p[j][3]);
            *(uint2*)&Ps[qloc][j * 16 + lh * 4] = pk;
        }

        // rescale o: o[j][r] is q-row (lh*4+r); its alpha lives at lane 4lh+r
        float a_r[4];
#pragma unroll
        for (int r = 0; r < 4; ++r) a_r[r] = __shfl(alpha, lh * 4 + r);
#pragma unroll
        for (int j = 0; j < 4; ++j)
#pragma unroll
            for (int r = 0; r < 4; ++r) o[j][r] *= a_r[r];

        // O += P V : a = P rows (q), b = V^T rows (d)
        half8 aP0 = *(const half8*)&Ps[qloc][lh * 8];
        half8 aP1 = *(const half8*)&Ps[qloc][32 + lh * 8];
#pragma unroll
        for (int j = 0; j < 4; ++j) {
            half8 bV0 = *(const half8*)&Vs[j * 16 + ln][lh * 8];
            half8 bV1 = *(const half8*)&Vs[j * 16 + ln][32 + lh * 8];
            o[j] = __builtin_amdgcn_mfma_f32_16x16x32_f16(aP0, bV0, o[j], 0, 0, 0);
            o[j] = __builtin_amdgcn_mfma_f32_16x16x32_f16(aP1, bV1, o[j], 0, 0, 0);
        }
        __syncthreads();   // all reads of Ks/Vs done before next staging
    }

    // epilogue: o rows = q-local lh*4+r, cols d = 16j+ln
#pragma unroll
    for (int r = 0; r < 4; ++r) {
        const float lr = __shfl(l_i, lh * 4 + r);
        const float il = 1.0f / lr;
        const int qrow = qb * 64 + qr0 + lh * 4 + r;
#pragma unroll
        for (int j = 0; j < 4; ++j) {
            const int d = j * 16 + ln;
            AV[((size_t)qrow * BB + b) * DMODEL + h * 64 + d] = f2h(o[j][r] * il);
        }
    }
}

// ---------------------------------------------------------------------------
extern "C" void kernel_launch(void* const* d_in, const int* in_sizes, int n_in,
                              void* d_out, int out_size, void* d_ws, size_t ws_size,
                              hipStream_t stream)
{
    const float* x      = (const float*)d_in[0];
    const float* qkv_w  = (const float*)d_in[1];
    const float* qkv_b  = (const float*)d_in[2];
    const float* out_w  = (const float*)d_in[3];
    const float* out_b  = (const float*)d_in[4];
    const int*   is_causal = (const int*)d_in[5];
    float* out = (float*)d_out;

    u16* ws   = (u16*)d_ws;
    u16* xb   = ws;                       // 4096*1024
    u16* wqkv = xb   + (size_t)4194304;   // 3072*1024
    u16* wout = wqkv + (size_t)3145728;   // 1024*1024
    u16* Qh   = wout + (size_t)1048576;   // [b][h][t][d]
    u16* Kh   = Qh   + (size_t)4194304;   // [b][h][t][d]
    u16* Vth  = Kh   + (size_t)4194304;   // [b][h][d][t]
    u16* AVh  = Vth  + (size_t)4194304;   // 4096*1024

    cast3_f32_f16<<<8192, 256, 0, stream>>>(x, xb, qkv_w, wqkv, out_w, wout);

    // QKV projection: M=4096, N=3072, K=1024 (Q scaled, V transposed)
    gemm_f16<1><<<dim3(3 * DMODEL / 64, MROWS / 128), 256, 0, stream>>>(
        xb, wqkv, qkv_b, nullptr, Qh, Kh, Vth, MROWS, 3 * DMODEL, DMODEL);

    // flash attention: 1024 blocks, one 64-row q-tile each, 4 resident/CU
    flash_f16<<<1024, 256, 0, stream>>>(Qh, Kh, Vth, AVh, is_causal);

    // output projection: M=4096, N=1024, K=1024 (fp32 out)
    gemm_f16<0><<<dim3(DMODEL / 64, MROWS / 128), 256, 0, stream>>>(
        AVh, wout, out_b, out, nullptr, nullptr, nullptr, MROWS, DMODEL, DMODEL);
}

// Round 9
// 189.982 us; speedup vs baseline: 1.2534x; 1.0281x over previous
//
#include <hip/hip_runtime.h>
#include <math.h>

#define TSEQ   2048
#define BB     2
#define DMODEL 1024
#define NHEAD  16
#define DHEAD  64
#define MROWS  (TSEQ * BB)   // 4096
#define NQB    (TSEQ / 64)   // 32 query tiles per (b,h)

typedef __attribute__((ext_vector_type(8))) _Float16 half8;
typedef __attribute__((ext_vector_type(4))) float    floatx4;
typedef unsigned short u16;
typedef unsigned int   u32;

#define QSCL 11.5415603f   /* 8 * log2(e): Q pre-scale -> exp2-domain scores */
#define MSK  1442695.0f    /* 1e6 * log2(e) */

__device__ __forceinline__ u16 f2h(float f) {
    union { _Float16 h; u16 u; } cv;
    cv.h = (_Float16)f;
    return cv.u;
}

// packed fp32x2 -> fp16x2 (round-to-zero) as u32
__device__ __forceinline__ u32 pkrtz(float a, float b) {
    typedef __attribute__((ext_vector_type(2))) __fp16 fp16x2;
    union { fp16x2 h; u32 u; } cv;
    cv.h = __builtin_amdgcn_cvt_pkrtz(a, b);
    return cv.u;
}

__device__ __forceinline__ void async_cp16(const u16* g, u16* l) {
    __builtin_amdgcn_global_load_lds(
        (const __attribute__((address_space(1))) unsigned int*)g,
        (__attribute__((address_space(3))) unsigned int*)l, 16, 0, 0);
}

// ---------------------------------------------------------------------------
// one-launch fp32 -> fp16 cast of x, qkv_w, out_w
// float4 units: x 1048576, qkv_w 786432, out_w 262144 (total 2097152)
// ---------------------------------------------------------------------------
__global__ __launch_bounds__(256)
void cast3_f32_f16(const float* __restrict__ a, u16* __restrict__ oa,
                   const float* __restrict__ b, u16* __restrict__ ob,
                   const float* __restrict__ c, u16* __restrict__ oc)
{
    int i = blockIdx.x * 256 + threadIdx.x;
    const float* src; u16* dst; int off;
    if (i < 1048576)      { src = a; dst = oa; off = 0; }
    else if (i < 1835008) { src = b; dst = ob; off = 1048576; }
    else                  { src = c; dst = oc; off = 1835008; }
    int j = i - off;
    float4 v = ((const float4*)src)[j];
    ushort4 o;
    o.x = f2h(v.x); o.y = f2h(v.y); o.z = f2h(v.z); o.w = f2h(v.w);
    ((ushort4*)dst)[j] = o;
}

// ---------------------------------------------------------------------------
// QKV GEMM: 128(M) x 64(N) tile, BK=64, global_load_lds + XOR-swizzled LDS.
// c<2 (Q,K): transposed orientation, packed uint2 fp16 -> [b][h][t][d],
//            Q scaled by QSCL;  c==2 (V): normal -> V^T [b][h][d][t].
// ---------------------------------------------------------------------------
__global__ __launch_bounds__(256)
void gemm_qkv(const u16* __restrict__ A, const u16* __restrict__ W,
              const float* __restrict__ bias,
              u16* __restrict__ Qo, u16* __restrict__ Ko, u16* __restrict__ Vo,
              int M, int N, int K)
{
    __shared__ __align__(16) u16 As[128][64];
    __shared__ __align__(16) u16 Bs[64][64];

    const int tid  = threadIdx.x;
    const int lane = tid & 63;
    const int wv   = tid >> 6;
    const int ln   = lane & 15, lh = lane >> 4;
    const int m0   = blockIdx.y * 128;
    const int n0   = blockIdx.x * 64;

    const int c = n0 >> 10;                  // 0,1,2 = q,k,v (block-uniform)
    const bool vmode = (c == 2);             // normal orientation

    const int srowA = wv * 32 + (lane >> 3);
    const int srowW = wv * 16 + (lane >> 3);
    const int sslot = lane & 7;

    const floatx4 zero4 = {0.0f, 0.0f, 0.0f, 0.0f};
    floatx4 acc[2][4];
#pragma unroll
    for (int i = 0; i < 2; ++i)
#pragma unroll
        for (int j = 0; j < 4; ++j) acc[i][j] = zero4;

    for (int k0 = 0; k0 < K; k0 += 64) {
        __syncthreads();
#pragma unroll
        for (int t = 0; t < 4; ++t) {
            const int row = srowA + t * 8;
            const int g   = sslot ^ (row & 7);
            async_cp16(A + (size_t)(m0 + row) * K + k0 + g * 8, &As[row][sslot * 8]);
        }
#pragma unroll
        for (int t = 0; t < 2; ++t) {
            const int row = srowW + t * 8;
            const int g   = sslot ^ (row & 7);
            async_cp16(W + (size_t)(n0 + row) * K + k0 + g * 8, &Bs[row][sslot * 8]);
        }
        __syncthreads();

#pragma unroll
        for (int ks = 0; ks < 2; ++ks) {
            half8 xf[2], wf[4];
#pragma unroll
            for (int i = 0; i < 2; ++i) {
                const int row = wv * 32 + i * 16 + ln;
                xf[i] = *(const half8*)&As[row][(((ks << 2) | lh) ^ (row & 7)) * 8];
            }
#pragma unroll
            for (int j = 0; j < 4; ++j) {
                const int row = j * 16 + ln;
                wf[j] = *(const half8*)&Bs[row][(((ks << 2) | lh) ^ (row & 7)) * 8];
            }
            if (vmode) {
#pragma unroll
                for (int i = 0; i < 2; ++i)
#pragma unroll
                    for (int j = 0; j < 4; ++j)
                        acc[i][j] = __builtin_amdgcn_mfma_f32_16x16x32_f16(xf[i], wf[j], acc[i][j], 0, 0, 0);
            } else {
#pragma unroll
                for (int i = 0; i < 2; ++i)
#pragma unroll
                    for (int j = 0; j < 4; ++j)
                        acc[i][j] = __builtin_amdgcn_mfma_f32_16x16x32_f16(wf[j], xf[i], acc[i][j], 0, 0, 0);
            }
        }
    }

    if (!vmode) {
        // Q/K transposed: feature nb..nb+3 consecutive in acc regs
        const float scl = (c == 0) ? QSCL : 1.0f;
        u16* dst = (c == 0) ? Qo : Ko;
#pragma unroll
        for (int j = 0; j < 4; ++j) {
            const int nb = n0 + j * 16 + lh * 4;
            const float4 b4 = *(const float4*)&bias[nb];
            const int h  = (nb >> 6) & 15;
            const int d0 = nb & 63;
#pragma unroll
            for (int i = 0; i < 2; ++i) {
                const int tok = m0 + wv * 32 + i * 16 + ln;
                const int t = tok >> 1, b = tok & 1;
                uint2 pk;
                pk.x = pkrtz((acc[i][j][0] + b4.x) * scl, (acc[i][j][1] + b4.y) * scl);
                pk.y = pkrtz((acc[i][j][2] + b4.z) * scl, (acc[i][j][3] + b4.w) * scl);
                *(uint2*)&dst[(((size_t)b * NHEAD + h) * TSEQ + t) * DHEAD + d0] = pk;
            }
        }
    } else {
        // V normal: rows = token (lh*4+p), cols = feature (ln) -> V^T stores
#pragma unroll
        for (int j = 0; j < 4; ++j) {
            const int col = n0 + j * 16 + ln;
            const float bc = bias[col];
            const int h = (col >> 6) & 15;
            const int d = col & 63;
#pragma unroll
            for (int i = 0; i < 2; ++i) {
                const int mb = m0 + wv * 32 + i * 16 + lh * 4;
                const int t0 = mb >> 1;
                const u32 e0 = pkrtz(acc[i][j][0] + bc, acc[i][j][2] + bc);  // b=0
                const u32 e1 = pkrtz(acc[i][j][1] + bc, acc[i][j][3] + bc);  // b=1
                *(u32*)&Vo[(((size_t)0 * NHEAD + h) * DHEAD + d) * TSEQ + t0] = e0;
                *(u32*)&Vo[(((size_t)1 * NHEAD + h) * DHEAD + d) * TSEQ + t0] = e1;
            }
        }
    }
}

// ---------------------------------------------------------------------------
// out-proj GEMM: 64x64 tile, BK=64; grid (16,64)=1024 blocks -> 4/CU
// (the 128x64 version ran at 2 blocks/CU and was latency-starved).
// Transposed orientation -> float4 fp32 stores of C = A*W^T + bias.
// ---------------------------------------------------------------------------
__global__ __launch_bounds__(256)
void gemm_out64(const u16* __restrict__ A, const u16* __restrict__ W,
                const float* __restrict__ bias, float* __restrict__ Cout,
                int M, int N, int K)
{
    __shared__ __align__(16) u16 As[64][64];
    __shared__ __align__(16) u16 Bs[64][64];

    const int tid  = threadIdx.x;
    const int lane = tid & 63;
    const int wv   = tid >> 6;
    const int ln   = lane & 15, lh = lane >> 4;
    const int m0   = blockIdx.y * 64;
    const int n0   = blockIdx.x * 64;

    const floatx4 zero4 = {0.0f, 0.0f, 0.0f, 0.0f};
    floatx4 acc[4];
#pragma unroll
    for (int j = 0; j < 4; ++j) acc[j] = zero4;

    for (int k0 = 0; k0 < K; k0 += 64) {
        __syncthreads();
#pragma unroll
        for (int cb = 0; cb < 2; ++cb) {
            const int idx  = cb * 256 + tid;
            const int row  = idx >> 3;
            const int slot = idx & 7;
            const int g    = slot ^ (row & 7);
            async_cp16(A + (size_t)(m0 + row) * K + k0 + g * 8, &As[row][slot * 8]);
            async_cp16(W + (size_t)(n0 + row) * K + k0 + g * 8, &Bs[row][slot * 8]);
        }
        __syncthreads();

#pragma unroll
        for (int ks = 0; ks < 2; ++ks) {
            const int arow = wv * 16 + ln;
            half8 xf = *(const half8*)&As[arow][(((ks << 2) | lh) ^ (arow & 7)) * 8];
#pragma unroll
            for (int j = 0; j < 4; ++j) {
                const int row = j * 16 + ln;
                half8 wf = *(const half8*)&Bs[row][(((ks << 2) | lh) ^ (row & 7)) * 8];
                acc[j] = __builtin_amdgcn_mfma_f32_16x16x32_f16(wf, xf, acc[j], 0, 0, 0);
            }
        }
    }

    // transposed: D rows = feature (lh*4+p), cols = token (ln)
#pragma unroll
    for (int j = 0; j < 4; ++j) {
        const int fb = n0 + j * 16 + lh * 4;
        const float4 b4 = *(const float4*)&bias[fb];
        const int tok = m0 + wv * 16 + ln;
        float4 v;
        v.x = acc[j][0] + b4.x;
        v.y = acc[j][1] + b4.y;
        v.z = acc[j][2] + b4.z;
        v.w = acc[j][3] + b4.w;
        *(float4*)&Cout[(size_t)tok * N + fb] = v;
    }
}

// ---------------------------------------------------------------------------
// S^T-formulation MFMA flash attention, 64-q-row tiles, one tile per block.
// Grid 1024 -> 4 resident blocks/CU; LDS 30.0 KB (Qs aliased with Ps: Q is
// only read in the prologue; first P write is after a later barrier - safe).
// l_i via ones-column: V^T tile has a ones d-row (row 64); the PV MFMA then
// accumulates row-sums of P into o4 with the same alpha recurrence ->
// removes 16 adds + 2 shuffles + 2 FMA per iteration from the VALU path.
// Causal balance: 4 dispatch phases map slot j to qb {31-j, j, 23-j, 8+j}.
// ---------------------------------------------------------------------------
__global__ __launch_bounds__(256)
void flash_f16(const u16* __restrict__ Q, const u16* __restrict__ K,
               const u16* __restrict__ Vt, u16* __restrict__ AV,
               const int* __restrict__ causal_p)
{
    // layout: rows 0..63 = Q then P (aliased); 64..127 = K; 128..207 = V^T+ones
    __shared__ __align__(16) u16 smem[(64 + 64 + 80) * 72];
    u16 (* __restrict__ QPs)[72] = (u16(*)[72])smem;
    u16 (* __restrict__ Ks)[72]  = (u16(*)[72])(smem + 64 * 72);
    u16 (* __restrict__ Vs)[72]  = (u16(*)[72])(smem + 128 * 72);

    const int tid  = threadIdx.x;
    const int lane = tid & 63;
    const int wv   = tid >> 6;
    const int ln   = lane & 15, lh = lane >> 4;

    const int phase = blockIdx.x >> 8;          // 0..3
    const int slot  = blockIdx.x & 255;
    const int bh    = slot & 31;                // b*16 + h
    const int jq    = slot >> 5;                // 0..7
    int qb;
    if      (phase == 0) qb = 31 - jq;
    else if (phase == 1) qb = jq;
    else if (phase == 2) qb = 23 - jq;
    else                 qb = 8 + jq;

    const int b = bh >> 4;
    const int h = bh & 15;
    const int causal = causal_p[0];

    const u16* Qg = Q  + (size_t)bh * TSEQ * DHEAD;
    const u16* Kg = K  + (size_t)bh * TSEQ * DHEAD;
    const u16* Vg = Vt + (size_t)bh * DHEAD * TSEQ;

    const int lrow = tid >> 3;                  // 0..31
    const int lc8  = (tid & 7) * 8;

    // Q tile -> LDS (QPs); ones rows 64..79 of Vs; prefetch K/V^T block 0
    *(uint4*)&QPs[lrow][lc8]      = *(const uint4*)(Qg + (size_t)(qb * 64 + lrow) * DHEAD + lc8);
    *(uint4*)&QPs[lrow + 32][lc8] = *(const uint4*)(Qg + (size_t)(qb * 64 + lrow + 32) * DHEAD + lc8);
    for (int idx = tid; idx < 16 * 72; idx += 256) {
        const int rr = idx / 72, cc = idx % 72;
        Vs[64 + rr][cc] = (rr == 0) ? (u16)0x3C00 : (u16)0;   // fp16 1.0 / 0
    }
    uint4 kreg0 = *(const uint4*)(Kg + (size_t)lrow * DHEAD + lc8);
    uint4 kreg1 = *(const uint4*)(Kg + (size_t)(lrow + 32) * DHEAD + lc8);
    uint4 vreg0 = *(const uint4*)(Vg + (size_t)lrow * TSEQ + lc8);
    uint4 vreg1 = *(const uint4*)(Vg + (size_t)(lrow + 32) * TSEQ + lc8);
    __syncthreads();

    const int qr0  = wv * 16;
    const int qloc = qr0 + ln;                  // this lane's q-row (local)
    const half8 bQ0 = *(const half8*)&QPs[qloc][lh * 8];
    const half8 bQ1 = *(const half8*)&QPs[qloc][32 + lh * 8];
    // ones-row B-frags (loop-invariant: rows 64..79 never re-staged)
    const half8 bO0 = *(const half8*)&Vs[64 + ln][lh * 8];
    const half8 bO1 = *(const half8*)&Vs[64 + ln][32 + lh * 8];

    const floatx4 zero4 = {0.0f, 0.0f, 0.0f, 0.0f};
    floatx4 o[4], o4;
#pragma unroll
    for (int j = 0; j < 4; ++j) o[j] = zero4;
    o4 = zero4;
    float m_i = -3.0e38f;

    const int kb_end = causal ? qb : (TSEQ / 64 - 1);
    for (int kb = 0; kb <= kb_end; ++kb) {
        // stage prefetched regs -> LDS (straight copies)
        *(uint4*)&Ks[lrow][lc8]      = kreg0;
        *(uint4*)&Ks[lrow + 32][lc8] = kreg1;
        *(uint4*)&Vs[lrow][lc8]      = vreg0;
        *(uint4*)&Vs[lrow + 32][lc8] = vreg1;
        __syncthreads();

        // prefetch next K/V^T block (hidden behind compute)
        if (kb < kb_end) {
            const size_t nk = (size_t)(kb + 1) * 64;
            kreg0 = *(const uint4*)(Kg + (nk + lrow) * DHEAD + lc8);
            kreg1 = *(const uint4*)(Kg + (nk + lrow + 32) * DHEAD + lc8);
            vreg0 = *(const uint4*)(Vg + (size_t)lrow * TSEQ + nk + lc8);
            vreg1 = *(const uint4*)(Vg + (size_t)(lrow + 32) * TSEQ + nk + lc8);
        }

        // S^T = K Q^T : s[j][r] = S[key = 16j+4lh+r][q = qloc]
        floatx4 s[4];
#pragma unroll
        for (int j = 0; j < 4; ++j) {
            half8 aK0 = *(const half8*)&Ks[j * 16 + ln][lh * 8];
            half8 aK1 = *(const half8*)&Ks[j * 16 + ln][32 + lh * 8];
            floatx4 z = zero4;
            z = __builtin_amdgcn_mfma_f32_16x16x32_f16(aK0, bQ0, z, 0, 0, 0);
            z = __builtin_amdgcn_mfma_f32_16x16x32_f16(aK1, bQ1, z, 0, 0, 0);
            s[j] = z;
        }
        if ((causal != 0) && (kb == qb)) {
#pragma unroll
            for (int j = 0; j < 4; ++j)
#pragma unroll
                for (int r = 0; r < 4; ++r)
                    if (j * 16 + lh * 4 + r > qloc) s[j][r] -= MSK;
        }

        // per-lane online max (one q-row per lane; reduce across lh groups)
        float mx = m_i;
#pragma unroll
        for (int j = 0; j < 4; ++j)
#pragma unroll
            for (int r = 0; r < 4; ++r) mx = fmaxf(mx, s[j][r]);
        mx = fmaxf(mx, __shfl_xor(mx, 16));
        mx = fmaxf(mx, __shfl_xor(mx, 32));
        const float alpha = exp2f(m_i - mx);
        m_i = mx;

        // P = exp2(s - mx), packed straight to LDS (rows wave-private)
#pragma unroll
        for (int j = 0; j < 4; ++j) {
            uint2 pk;
            pk.x = pkrtz(exp2f(s[j][0] - mx), exp2f(s[j][1] - mx));
            pk.y = pkrtz(exp2f(s[j][2] - mx), exp2f(s[j][3] - mx));
            *(uint2*)&QPs[qloc][j * 16 + lh * 4] = pk;
        }

        // rescale o (and o4): o[j][r] is q-row (lh*4+r); alpha at lane 4lh+r
        float a_r[4];
#pragma unroll
        for (int r = 0; r < 4; ++r) a_r[r] = __shfl(alpha, lh * 4 + r);
#pragma unroll
        for (int j = 0; j < 4; ++j)
#pragma unroll
            for (int r = 0; r < 4; ++r) o[j][r] *= a_r[r];
#pragma unroll
        for (int r = 0; r < 4; ++r) o4[r] *= a_r[r];

        // O += P V ; o4 += P * ones (row-sums -> l_i recurrence for free)
        half8 aP0 = *(const half8*)&QPs[qloc][lh * 8];
        half8 aP1 = *(const half8*)&QPs[qloc][32 + lh * 8];
#pragma unroll
        for (int j = 0; j < 4; ++j) {
            half8 bV0 = *(const half8*)&Vs[j * 16 + ln][lh * 8];
            half8 bV1 = *(const half8*)&Vs[j * 16 + ln][32 + lh * 8];
            o[j] = __builtin_amdgcn_mfma_f32_16x16x32_f16(aP0, bV0, o[j], 0, 0, 0);
            o[j] = __builtin_amdgcn_mfma_f32_16x16x32_f16(aP1, bV1, o[j], 0, 0, 0);
        }
        o4 = __builtin_amdgcn_mfma_f32_16x16x32_f16(aP0, bO0, o4, 0, 0, 0);
        o4 = __builtin_amdgcn_mfma_f32_16x16x32_f16(aP1, bO1, o4, 0, 0, 0);

        __syncthreads();   // all reads of Ks/Vs/QPs done before next staging
    }

    // epilogue: o rows = q-local lh*4+r, cols d = 16j+ln.
    // l of q-row 4lh'+r lives in o4[r] of lane 16*lh' (column d=64 -> ln=0).
#pragma unroll
    for (int r = 0; r < 4; ++r) {
        const float lr = __shfl(o4[r], lane & 48);
        const float il = 1.0f / lr;
        const int qrow = qb * 64 + qr0 + lh * 4 + r;
#pragma unroll
        for (int j = 0; j < 4; ++j) {
            const int d = j * 16 + ln;
            AV[((size_t)qrow * BB + b) * DMODEL + h * 64 + d] = f2h(o[j][r] * il);
        }
    }
}

// ---------------------------------------------------------------------------
extern "C" void kernel_launch(void* const* d_in, const int* in_sizes, int n_in,
                              void* d_out, int out_size, void* d_ws, size_t ws_size,
                              hipStream_t stream)
{
    const float* x      = (const float*)d_in[0];
    const float* qkv_w  = (const float*)d_in[1];
    const float* qkv_b  = (const float*)d_in[2];
    const float* out_w  = (const float*)d_in[3];
    const float* out_b  = (const float*)d_in[4];
    const int*   is_causal = (const int*)d_in[5];
    float* out = (float*)d_out;

    u16* ws   = (u16*)d_ws;
    u16* xb   = ws;                       // 4096*1024
    u16* wqkv = xb   + (size_t)4194304;   // 3072*1024
    u16* wout = wqkv + (size_t)3145728;   // 1024*1024
    u16* Qh   = wout + (size_t)1048576;   // [b][h][t][d]
    u16* Kh   = Qh   + (size_t)4194304;   // [b][h][t][d]
    u16* Vth  = Kh   + (size_t)4194304;   // [b][h][d][t]
    u16* AVh  = Vth  + (size_t)4194304;   // 4096*1024

    cast3_f32_f16<<<8192, 256, 0, stream>>>(x, xb, qkv_w, wqkv, out_w, wout);

    // QKV projection: M=4096, N=3072, K=1024 (Q scaled, V transposed)
    gemm_qkv<<<dim3(3 * DMODEL / 64, MROWS / 128), 256, 0, stream>>>(
        xb, wqkv, qkv_b, Qh, Kh, Vth, MROWS, 3 * DMODEL, DMODEL);

    // flash attention: 1024 blocks, one 64-row q-tile each, 4 resident/CU
    flash_f16<<<1024, 256, 0, stream>>>(Qh, Kh, Vth, AVh, is_causal);

    // output projection: M=4096, N=1024, K=1024, 64x64 tiles -> 4 blocks/CU
    gemm_out64<<<dim3(DMODEL / 64, MROWS / 64), 256, 0, stream>>>(
        AVh, wout, out_b, out, MROWS, DMODEL, DMODEL);
}